// Round 3
// baseline (457.127 us; speedup 1.0000x reference)
//
#include <hip/hip_runtime.h>

// Subtractor50Bit: A - B via two's complement, N rows x 50 bits ({0,1} floats).
// out = [result (N*50 floats), borrow (N floats)].
//
// R2: software pipeline across tiles. Each wave owns several 64-row tiles
// (grid-stride). Per iteration: ballots consume tile t's fa/fb registers,
// then ALL loads for tile t+1 are issued, then the long shuffle/store phase
// of tile t runs while those loads are in flight. This keeps ~25KB of
// outstanding loads per wave during the store phase (vs ~2KB in R1),
// unblocking HBM bandwidth. Ballot/compute/store logic identical to the
// passing R1 kernel.

constexpr int BITS = 50;
constexpr unsigned long long MASK50 = (1ULL << BITS) - 1ULL;
constexpr int ROWS_PER_TILE = 64;
constexpr int ELEMS_PER_TILE = ROWS_PER_TILE * BITS;   // 3200

__device__ inline unsigned long long shfl64(unsigned long long v, int src) {
    int lo = __shfl((int)(unsigned)(v & 0xffffffffULL), src, 64);
    int hi = __shfl((int)(unsigned)(v >> 32), src, 64);
    return ((unsigned long long)(unsigned)hi << 32) | (unsigned long long)(unsigned)lo;
}

__global__ __launch_bounds__(256, 2) void Subtractor50Bit_kernel(
    const float* __restrict__ A, const float* __restrict__ B,
    float* __restrict__ out, int N, int numTiles, int waveStride)
{
    const int lane = threadIdx.x & 63;

    // Leftover rows (N % 64) — scalar path, first wave only (none for N=1e6).
    if (blockIdx.x == 0 && threadIdx.x < 64) {
        long long r = (long long)numTiles * ROWS_PER_TILE + lane;
        if (r < N) {
            unsigned long long av = 0, bv = 0;
            for (int k = 0; k < BITS; ++k) {
                av |= (unsigned long long)(A[r * BITS + k] != 0.0f) << k;
                bv |= (unsigned long long)(B[r * BITS + k] != 0.0f) << k;
            }
            unsigned long long diff = (av - bv) & MASK50;
            for (int k = 0; k < BITS; ++k)
                out[r * BITS + k] = (float)((diff >> k) & 1ULL);
            out[(long long)N * BITS + r] = (av < bv) ? 1.0f : 0.0f;
        }
    }

    long long t = (long long)blockIdx.x * 4 + (threadIdx.x >> 6);
    if (t >= numTiles) return;

    const int p0   = BITS * lane;     // first bit position of my row
    const int idx0 = p0 >> 6;         // ballot word holding bit p0
    const int sh   = p0 & 63;
    const long long borrowBase = (long long)N * BITS;

    // Prologue: load tile t (interleaved fa/fb so ballot j waits on 2j,2j+1).
    float fa[BITS], fb[BITS];
    {
        const float* pa = A + t * ELEMS_PER_TILE + lane;
        const float* pb = B + t * ELEMS_PER_TILE + lane;
        #pragma unroll
        for (int j = 0; j < BITS; ++j) {
            fa[j] = pa[j * 64];
            fb[j] = pb[j * 64];
        }
    }

    for (;;) {
        // Phase A: ballots consume fa/fb; lane j captures ballot word j.
        unsigned long long wa = 0, wb = 0;
        #pragma unroll
        for (int j = 0; j < BITS; ++j) {
            unsigned long long ma = __ballot(fa[j] != 0.0f);
            unsigned long long mb = __ballot(fb[j] != 0.0f);
            if (lane == j) { wa = ma; wb = mb; }
        }

        const long long eBase = t * ELEMS_PER_TILE;
        const long long nt    = t + waveStride;
        const bool more       = nt < numTiles;

        // Phase B: issue ALL of next tile's loads now; they fly during Phase C.
        if (more) {
            const float* pa = A + nt * ELEMS_PER_TILE + lane;
            const float* pb = B + nt * ELEMS_PER_TILE + lane;
            #pragma unroll
            for (int j = 0; j < BITS; ++j) {
                fa[j] = pa[j * 64];
                fb[j] = pb[j * 64];
            }
        }

        // Phase C: distribute ballot words, compute, coalesced store (tile t).
        unsigned long long a0 = shfl64(wa, idx0);
        unsigned long long a1 = shfl64(wa, idx0 + 1);
        unsigned long long b0 = shfl64(wb, idx0);
        unsigned long long b1 = shfl64(wb, idx0 + 1);

        unsigned long long av = a0 >> sh;
        unsigned long long bv = b0 >> sh;
        if (sh > 64 - BITS) {           // need bits from the next word
            av |= a1 << (64 - sh);
            bv |= b1 << (64 - sh);
        }
        av &= MASK50;
        bv &= MASK50;

        unsigned long long diff = (av - bv) & MASK50;  // sum bits of A + ~B + 1
        float borrow = (av < bv) ? 1.0f : 0.0f;        // 1 - carry_out

        #pragma unroll
        for (int j = 0; j < BITS; ++j) {
            int local = j * 64 + lane;      // [0, 3200)
            int r     = local / BITS;       // owning local row (magic-mul)
            int bit   = local - r * BITS;   // bit index within that row
            unsigned long long dr = shfl64(diff, r);
            out[eBase + local] = (float)((dr >> bit) & 1ULL);
        }
        out[borrowBase + t * ROWS_PER_TILE + lane] = borrow;

        if (!more) break;
        t = nt;
    }
}

extern "C" void kernel_launch(void* const* d_in, const int* in_sizes, int n_in,
                              void* d_out, int out_size, void* d_ws, size_t ws_size,
                              hipStream_t stream) {
    const float* A = (const float*)d_in[0];
    const float* B = (const float*)d_in[1];
    float* out = (float*)d_out;
    const int N = in_sizes[0] / BITS;          // 1,000,000

    const int numTiles   = N / ROWS_PER_TILE;  // full 64-row tiles (15625)
    const int blocks     = 1024;               // ~4 tiles/wave grid-stride
    const int waveStride = blocks * 4;         // total waves
    Subtractor50Bit_kernel<<<blocks, 256, 0, stream>>>(A, B, out, N, numTiles, waveStride);
}